// Round 8
// baseline (2794.075 us; speedup 1.0000x reference)
//
#include <hip/hip_runtime.h>
#include <hip/hip_bf16.h>

#define B_ 256
#define T_ 512
#define IN_ 202
#define HID_ 100
#define K_ 19

__device__ __forceinline__ float rl_f(float v, int l) {
  return __int_as_float(__builtin_amdgcn_readlane(__float_as_int(v), l));
}

// ---------------- K1: pre[row*200 + c] = x . [wf;wb]^T + bias, both dirs fused.
// Round-5 proven body (297 us). launch_bounds min-waves 3 to allow 3 blocks/CU
// (LDS 45.5KB x3 = 136KB < 160KB; VGPR cap 170 > 128 used).
__global__ __launch_bounds__(256, 3) void k_ih(
    const float* __restrict__ x,
    const float* __restrict__ wf, const float* __restrict__ wb,
    const float* __restrict__ bif, const float* __restrict__ bhf,
    const float* __restrict__ bib, const float* __restrict__ bhb,
    float* __restrict__ pre) {
  __shared__ float2 xs[128][17];   // [row][kpair], conflict-free (measured 0)
  __shared__ float2 wsm[200][17];  // [col][kpair]
  __shared__ float bsum[200];
  int tid = threadIdx.x;
  int cg = tid & 7, rg = tid >> 3;
  int c0 = cg * 25;
  int rowbase = rg * 4;
  long row0 = (long)blockIdx.x * 128;
  for (int u = tid; u < 200; u += 256)
    bsum[u] = (u < 100) ? (bif[u] + bhf[u]) : (bib[u - 100] + bhb[u - 100]);
  float acc[4][25];
#pragma unroll
  for (int r = 0; r < 4; r++)
#pragma unroll
    for (int j = 0; j < 25; j++) acc[r][j] = 0.f;

  for (int ck = 0; ck < 7; ck++) {
    int k0 = ck * 32;
    __syncthreads();
    for (int u = tid; u < 2048; u += 256) {
      int r = u >> 4, kp = u & 15;
      int gk = k0 + 2 * kp;
      float2 v = make_float2(0.f, 0.f);
      if (gk < IN_) v = *(const float2*)(x + (row0 + r) * IN_ + gk);
      xs[r][kp] = v;
    }
    for (int u = tid; u < 3200; u += 256) {
      int c = u >> 4, kp = u & 15;
      int gk = k0 + 2 * kp;
      float2 v = make_float2(0.f, 0.f);
      if (gk < IN_) {
        const float* src = (c < 100) ? (wf + c * IN_) : (wb + (c - 100) * IN_);
        v = *(const float2*)(src + gk);
      }
      wsm[c][kp] = v;
    }
    __syncthreads();
#pragma unroll 4
    for (int kk = 0; kk < 16; kk++) {
      float2 xv0 = xs[rowbase + 0][kk];
      float2 xv1 = xs[rowbase + 1][kk];
      float2 xv2 = xs[rowbase + 2][kk];
      float2 xv3 = xs[rowbase + 3][kk];
#pragma unroll
      for (int j = 0; j < 25; j++) {
        float2 wv = wsm[c0 + j][kk];
        acc[0][j] = fmaf(xv0.y, wv.y, fmaf(xv0.x, wv.x, acc[0][j]));
        acc[1][j] = fmaf(xv1.y, wv.y, fmaf(xv1.x, wv.x, acc[1][j]));
        acc[2][j] = fmaf(xv2.y, wv.y, fmaf(xv2.x, wv.x, acc[2][j]));
        acc[3][j] = fmaf(xv3.y, wv.y, fmaf(xv3.x, wv.x, acc[3][j]));
      }
    }
  }
#pragma unroll
  for (int rr = 0; rr < 4; rr++) {
    float* o = pre + (row0 + rowbase + rr) * 200 + c0;
#pragma unroll
    for (int j = 0; j < 25; j++) o[j] = acc[rr][j] + bsum[c0 + j];
  }
}

// ---------------- K2: recurrence over b (256 steps); 2 waves per (t,dir) chain,
// full K=100 per wave, ONE barrier per step. Wave0 rows 0..63, wave1 rows 64..99.
// W rows in registers (100 VGPR); h broadcast via uniform ds_read_b128 from
// double-buffered LDS. 1024 blocks x 2 waves -> 2 waves/SIMD (grid-limited).
__global__ __launch_bounds__(128, 2) void k_rnn(
    float* __restrict__ pre,
    const float* __restrict__ whf, const float* __restrict__ whb) {
  __shared__ float hb[2][104];
  int bid = blockIdx.x;
  int dir = bid >> 9;
  int t = bid & 511;
  const float* w = dir ? whb : whf;
  int tid = threadIdx.x;
  int wv = tid >> 6, lane = tid & 63;
  int row = wv ? (64 + (lane < 36 ? lane : 35)) : lane;
  bool owns = (!wv) || (lane < 36);
  float wr[HID_];
#pragma unroll
  for (int kk = 0; kk < 25; kk++) {
    float4 w4 = *(const float4*)(w + row * HID_ + 4 * kk);
    wr[4 * kk + 0] = w4.x; wr[4 * kk + 1] = w4.y;
    wr[4 * kk + 2] = w4.z; wr[4 * kk + 3] = w4.w;
  }
  long step = dir ? -(long)(T_ * 200) : (long)(T_ * 200);
  float* p = pre + ((long)(dir ? (B_ - 1) : 0) * T_ + t) * 200 + dir * 100;
  if (tid < 104) hb[0][tid] = 0.f;
  float a = p[row];
  __syncthreads();
  for (int s = 0; s < B_; s++) {
    int cur = s & 1;
    float a_next = 0.f;
    if (s < B_ - 1) a_next = p[step + row];
    float ac0 = a, ac1 = 0.f, ac2 = 0.f, ac3 = 0.f;
#pragma unroll
    for (int i = 0; i < 25; i++) {
      float4 h4 = *(const float4*)(&hb[cur][4 * i]);  // uniform addr -> broadcast
      ac0 = fmaf(h4.x, wr[4 * i + 0], ac0);
      ac1 = fmaf(h4.y, wr[4 * i + 1], ac1);
      ac2 = fmaf(h4.z, wr[4 * i + 2], ac2);
      ac3 = fmaf(h4.w, wr[4 * i + 3], ac3);
    }
    float hnew = tanhf((ac0 + ac1) + (ac2 + ac3));
    if (owns) {
      p[row] = hnew;
      hb[cur ^ 1][row] = hnew;
    }
    __syncthreads();
    p += step;
    a = a_next;
  }
}

// ---------------- K3: logits = h @ w_lin^T + b_lin ; softmax over 19. 2 rows/thread.
__global__ __launch_bounds__(256, 4) void k_lin(
    const float* __restrict__ h, const float* __restrict__ wlin,
    const float* __restrict__ blin, float* __restrict__ em) {
  int tid = threadIdx.x;
  long r0 = ((long)blockIdx.x * 256 + tid) * 2;
  const float* h0 = h + r0 * 200;
  float acc0[K_], acc1[K_];
#pragma unroll
  for (int c = 0; c < K_; c++) { float bb = blin[c]; acc0[c] = bb; acc1[c] = bb; }
  for (int kk = 0; kk < 50; kk++) {
    float4 a = *(const float4*)(h0 + 4 * kk);
    float4 b = *(const float4*)(h0 + 200 + 4 * kk);
#pragma unroll
    for (int c = 0; c < K_; c++) {
      float4 wv = *(const float4*)(wlin + c * 200 + 4 * kk);  // uniform -> s_load
      acc0[c] += a.x * wv.x + a.y * wv.y + a.z * wv.z + a.w * wv.w;
      acc1[c] += b.x * wv.x + b.y * wv.y + b.z * wv.z + b.w * wv.w;
    }
  }
  float mx0 = acc0[0], mx1 = acc1[0];
#pragma unroll
  for (int c = 1; c < K_; c++) { mx0 = fmaxf(mx0, acc0[c]); mx1 = fmaxf(mx1, acc1[c]); }
  float s0 = 0.f, s1 = 0.f;
#pragma unroll
  for (int c = 0; c < K_; c++) {
    acc0[c] = __expf(acc0[c] - mx0); s0 += acc0[c];
    acc1[c] = __expf(acc1[c] - mx1); s1 += acc1[c];
  }
  float i0 = 1.f / s0, i1 = 1.f / s1;
  float* e0 = em + r0 * K_;
#pragma unroll
  for (int c = 0; c < K_; c++) { e0[c] = acc0[c] * i0; e0[K_ + c] = acc1[c] * i1; }
}

// ---------------- K4: per-b CRF logZ + gold score (wave0) | Viterbi fwd + backtrack (wave1)
__global__ __launch_bounds__(128, 1) void k_crf(
    const float* __restrict__ em, const int* __restrict__ y,
    const float* __restrict__ st_g, const float* __restrict__ en_g,
    const float* __restrict__ tr_g,
    float* __restrict__ part, int* __restrict__ cnt,
    float* __restrict__ out) {
  __shared__ __align__(16) float es[T_ * K_];
  __shared__ int ys[T_];
  __shared__ float tr[K_ * K_];
  __shared__ float st[K_], en[K_];
  __shared__ unsigned char hl[511 * K_ + 13];
  __shared__ float lab[T_];
  int b = blockIdx.x;
  int tid = threadIdx.x;
  const float4* eb4 = (const float4*)(em + (long)b * T_ * K_);
  for (int u = tid; u < T_ * K_ / 4; u += 128) ((float4*)es)[u] = eb4[u];
  for (int u = tid; u < T_; u += 128) ys[u] = y[b * T_ + u];
  for (int u = tid; u < K_ * K_; u += 128) tr[u] = tr_g[u];
  if (tid < K_) { st[tid] = st_g[tid]; en[tid] = en_g[tid]; }
  __syncthreads();
  int wv = tid >> 6, lane = tid & 63;
  int jj = lane < K_ ? lane : K_ - 1;
  bool act = lane < K_;
  if (wv == 0) {
    float E[K_];
#pragma unroll
    for (int i = 0; i < K_; i++) E[i] = __expf(tr[i * K_ + jj]);
    float z = act ? st[jj] + es[jj] : -1e30f;
    int y0 = ys[0];
    int prev = (y0 != -1) ? y0 : 0;
    float num = st[prev] + es[prev];
    for (int t = 1; t < T_; t++) {
      float e = es[t * K_ + jj];
      int yv = ys[t];
      bool mb = (yv != -1);
      float m = z;
#pragma unroll
      for (int off = 16; off; off >>= 1) m = fmaxf(m, __shfl_xor(m, off, 32));
      float pz = __expf(z - m);
      float acca = 0.f, accb = 0.f;
#pragma unroll
      for (int i = 0; i < 9; i++)  acca = fmaf(rl_f(pz, i), E[i], acca);
#pragma unroll
      for (int i = 9; i < K_; i++) accb = fmaf(rl_f(pz, i), E[i], accb);
      float nz = e + m + __logf(acca + accb);
      if (act && mb) z = nz;
      if (mb) {
        num += tr[prev * K_ + yv] + es[t * K_ + yv];
        prev = yv;
      }
    }
    num += en[prev];
    float zf = z + en[jj];
    float m2 = zf;
#pragma unroll
    for (int off = 16; off; off >>= 1) m2 = fmaxf(m2, __shfl_xor(m2, off, 32));
    float sm = __expf(zf - m2);
#pragma unroll
    for (int off = 16; off; off >>= 1) sm += __shfl_xor(sm, off, 32);
    if (lane == 0) part[b] = m2 + __logf(sm) - num;
  } else {
    float Tt[K_];
#pragma unroll
    for (int i = 0; i < K_; i++) Tt[i] = tr[i * K_ + jj];
    float v = act ? st[jj] + es[jj] : -1e30f;
    for (int t = 1; t < T_; t++) {
      float e = es[t * K_ + jj];
      int yv = ys[t];
      bool mb = (yv != -1);
      float b0 = -1e30f, b1 = -1e30f, b2 = -1e30f, b3 = -1e30f;
      int a0 = 0, a1 = 5, a2 = 10, a3 = 15;
#pragma unroll
      for (int i = 0; i < 5; i++)  { float c = rl_f(v, i) + Tt[i]; if (c > b0) { b0 = c; a0 = i; } }
#pragma unroll
      for (int i = 5; i < 10; i++) { float c = rl_f(v, i) + Tt[i]; if (c > b1) { b1 = c; a1 = i; } }
#pragma unroll
      for (int i = 10; i < 15; i++){ float c = rl_f(v, i) + Tt[i]; if (c > b2) { b2 = c; a2 = i; } }
#pragma unroll
      for (int i = 15; i < 19; i++){ float c = rl_f(v, i) + Tt[i]; if (c > b3) { b3 = c; a3 = i; } }
      if (b1 > b0) { b0 = b1; a0 = a1; }
      if (b2 > b0) { b0 = b2; a0 = a2; }
      if (b3 > b0) { b0 = b3; a0 = a3; }
      if (act) hl[(t - 1) * K_ + lane] = (unsigned char)a0;
      if (act && mb) v = b0 + e;
    }
    float sc = v + en[jj];
    float bb = -1e30f; int aa = 0;
#pragma unroll
    for (int i = 0; i < K_; i++) { float c = rl_f(sc, i); if (c > bb) { bb = c; aa = i; } }
    int tag = aa;
    if (lane == 0) lab[T_ - 1] = (ys[T_ - 1] != -1) ? (float)tag : -1.f;
    int vc = (lane < K_) ? (int)hl[510 * K_ + lane] : 0;
    for (int ti = 510; ti >= 0; ti--) {
      int vn = 0;
      if (ti > 0 && lane < K_) vn = (int)hl[(ti - 1) * K_ + lane];
      int ts = __builtin_amdgcn_readfirstlane(tag);
      int cand = __builtin_amdgcn_readlane(vc, ts);
      tag = (ys[ti + 1] != -1) ? cand : tag;
      if (lane == 0) lab[ti] = (ys[ti] != -1) ? (float)tag : -1.f;
      vc = vn;
    }
  }
  __syncthreads();
  if (wv == 1) {
    float* ob = out + 1 + (long)b * T_;
    for (int u = lane; u < T_; u += 64) ob[u] = lab[u];
  } else {
    int old = -1;
    if (lane == 0) { __threadfence(); old = atomicAdd(cnt, 1); }
    old = __shfl(old, 0, 64);
    if (old == B_ - 1) {  // last block: deterministic fixed-order sum
      __threadfence();
      float s = 0.f;
      for (int u = lane; u < B_; u += 64) s += part[u];
#pragma unroll
      for (int off = 32; off; off >>= 1) s += __shfl_xor(s, off, 64);
      if (lane == 0) out[0] = s;
    }
  }
}

extern "C" void kernel_launch(void* const* d_in, const int* in_sizes, int n_in,
                              void* d_out, int out_size, void* d_ws, size_t ws_size,
                              hipStream_t stream) {
  const float* x      = (const float*)d_in[0];
  const int*   y      = (const int*)d_in[1];
  const float* w_ih_f = (const float*)d_in[2];
  const float* w_hh_f = (const float*)d_in[3];
  const float* b_ih_f = (const float*)d_in[4];
  const float* b_hh_f = (const float*)d_in[5];
  const float* w_ih_b = (const float*)d_in[6];
  const float* w_hh_b = (const float*)d_in[7];
  const float* b_ih_b = (const float*)d_in[8];
  const float* b_hh_b = (const float*)d_in[9];
  const float* w_lin  = (const float*)d_in[10];
  const float* b_lin  = (const float*)d_in[11];
  const float* st     = (const float*)d_in[12];
  const float* en     = (const float*)d_in[13];
  const float* trans  = (const float*)d_in[14];

  char* ws = (char*)d_ws;
  const size_t PRE_OFF  = 0;                          // 131072*200*4 = 104857600
  const size_t EM_OFF   = 104857600;                  // 131072*19*4  = 9961472
  const size_t PART_OFF = EM_OFF + 9961472;           // 1024
  const size_t CNT_OFF  = PART_OFF + 1024;            // 4
  float* PRE  = (float*)(ws + PRE_OFF);
  float* EM   = (float*)(ws + EM_OFF);
  float* PART = (float*)(ws + PART_OFF);
  int*   CNT  = (int*)(ws + CNT_OFF);
  float* out  = (float*)d_out;

  hipMemsetAsync((void*)CNT, 0, sizeof(int), stream);
  k_ih<<<1024, 256, 0, stream>>>(x, w_ih_f, w_ih_b, b_ih_f, b_hh_f, b_ih_b, b_hh_b, PRE);
  k_rnn<<<1024, 128, 0, stream>>>(PRE, w_hh_f, w_hh_b);
  k_lin<<<256, 256, 0, stream>>>(PRE, w_lin, b_lin, EM);
  k_crf<<<256, 128, 0, stream>>>(EM, y, st, en, trans, PART, CNT, out);
}

// Round 9
// 747.218 us; speedup vs baseline: 3.7393x; 3.7393x over previous
//
#include <hip/hip_runtime.h>
#include <hip/hip_bf16.h>

#define B_ 256
#define T_ 512
#define IN_ 202
#define HID_ 100
#define K_ 19

__device__ __forceinline__ float rl_f(float v, int l) {
  return __int_as_float(__builtin_amdgcn_readlane(__float_as_int(v), l));
}

// ---------------- K1: pre[row*200 + c] = x . [wf;wb]^T + bias, both dirs fused.
// Round-5 proven structure; K-chunk 24 (was 32) -> LDS 34.1KB -> 4 blocks/CU
// (VGPR 128 allows exactly 16 waves/CU). launch_bounds MUST stay (256,2):
// (256,3) made the compiler allocate 84 VGPRs and spill (round-8, 7.6x slower).
__global__ __launch_bounds__(256, 2) void k_ih(
    const float* __restrict__ x,
    const float* __restrict__ wf, const float* __restrict__ wb,
    const float* __restrict__ bif, const float* __restrict__ bhf,
    const float* __restrict__ bib, const float* __restrict__ bhb,
    float* __restrict__ pre) {
  __shared__ float2 xs[128][13];   // odd stride -> same bank pattern as proven [17]
  __shared__ float2 wsm[200][13];
  __shared__ float bsum[200];
  int tid = threadIdx.x;
  int cg = tid & 7, rg = tid >> 3;
  int c0 = cg * 25;
  int rowbase = rg * 4;
  long row0 = (long)blockIdx.x * 128;
  for (int u = tid; u < 200; u += 256)
    bsum[u] = (u < 100) ? (bif[u] + bhf[u]) : (bib[u - 100] + bhb[u - 100]);
  float acc[4][25];
#pragma unroll
  for (int r = 0; r < 4; r++)
#pragma unroll
    for (int j = 0; j < 25; j++) acc[r][j] = 0.f;

  for (int ck = 0; ck < 9; ck++) {
    int k0 = ck * 24;
    __syncthreads();
    // stage x: 128 rows x 12 f2 (gk even <= 200, so float2 stays in-bounds)
    for (int u = tid; u < 1536; u += 256) {
      int r = u / 12, kp = u - r * 12;
      int gk = k0 + 2 * kp;
      float2 v = make_float2(0.f, 0.f);
      if (gk < IN_) v = *(const float2*)(x + (row0 + r) * IN_ + gk);
      xs[r][kp] = v;
    }
    // stage w: 200 cols x 12 f2
    for (int u = tid; u < 2400; u += 256) {
      int c = u / 12, kp = u - c * 12;
      int gk = k0 + 2 * kp;
      float2 v = make_float2(0.f, 0.f);
      if (gk < IN_) {
        const float* src = (c < 100) ? (wf + c * IN_) : (wb + (c - 100) * IN_);
        v = *(const float2*)(src + gk);
      }
      wsm[c][kp] = v;
    }
    __syncthreads();
#pragma unroll 4
    for (int kk = 0; kk < 12; kk++) {
      float2 xv0 = xs[rowbase + 0][kk];
      float2 xv1 = xs[rowbase + 1][kk];
      float2 xv2 = xs[rowbase + 2][kk];
      float2 xv3 = xs[rowbase + 3][kk];
#pragma unroll
      for (int j = 0; j < 25; j++) {
        float2 wv = wsm[c0 + j][kk];
        acc[0][j] = fmaf(xv0.y, wv.y, fmaf(xv0.x, wv.x, acc[0][j]));
        acc[1][j] = fmaf(xv1.y, wv.y, fmaf(xv1.x, wv.x, acc[1][j]));
        acc[2][j] = fmaf(xv2.y, wv.y, fmaf(xv2.x, wv.x, acc[2][j]));
        acc[3][j] = fmaf(xv3.y, wv.y, fmaf(xv3.x, wv.x, acc[3][j]));
      }
    }
  }
#pragma unroll
  for (int rr = 0; rr < 4; rr++) {
    float* o = pre + (row0 + rowbase + rr) * 200 + c0;
#pragma unroll
    for (int j = 0; j < 25; j++) o[j] = acc[rr][j] + bsum[c0 + j];
  }
}

// ---------------- K2: recurrence over b (256 steps); 4 waves per (t,dir) chain.
// Round-5 proven version (237 us). Waves {0,1} rows 0..63, waves {2,3} rows
// 64..99; within a pair, k-slices [0,52)/[52,100). h broadcast via uniform
// ds_read_b128; partials via LDS; 2 barriers/step. 4 waves/SIMD.
template <int KO, int KN, bool OW>
__device__ __forceinline__ void rnn_loop(
    float* __restrict__ p, long step, int row, bool owns,
    const float* __restrict__ w, float (*hb)[104], float* __restrict__ ps) {
  float wr[KN];
#pragma unroll
  for (int i = 0; i < KN / 4; i++) {
    float4 w4 = *(const float4*)(w + row * HID_ + KO + 4 * i);
    wr[4 * i + 0] = w4.x; wr[4 * i + 1] = w4.y;
    wr[4 * i + 2] = w4.z; wr[4 * i + 3] = w4.w;
  }
  float a = 0.f;
  if (OW) a = p[row];
  for (int s = 0; s < B_; s++) {
    int cur = s & 1;
    float a_next = 0.f;
    if (OW && s < B_ - 1) a_next = p[step + row];
    float ac0 = OW ? a : 0.f, ac1 = 0.f, ac2 = 0.f, ac3 = 0.f;
#pragma unroll
    for (int i = 0; i < KN / 4; i++) {
      float4 h4 = *(const float4*)(&hb[cur][KO + 4 * i]);  // uniform addr -> broadcast
      ac0 = fmaf(h4.x, wr[4 * i + 0], ac0);
      ac1 = fmaf(h4.y, wr[4 * i + 1], ac1);
      ac2 = fmaf(h4.z, wr[4 * i + 2], ac2);
      ac3 = fmaf(h4.w, wr[4 * i + 3], ac3);
    }
    float partial = (ac0 + ac1) + (ac2 + ac3);
    if (!OW && owns) ps[row] = partial;
    __syncthreads();
    if (OW) {
      float hnew = tanhf(partial + ps[row]);
      if (owns) {
        hb[cur ^ 1][row] = hnew;
        p[row] = hnew;
      }
    }
    p += step;
    a = a_next;
    __syncthreads();
  }
}

__global__ __launch_bounds__(256, 4) void k_rnn(
    float* __restrict__ pre,
    const float* __restrict__ whf, const float* __restrict__ whb) {
  __shared__ float hb[2][104];
  __shared__ float ps[104];
  int bid = blockIdx.x;
  int dir = bid >> 9;
  int t = bid & 511;
  const float* w = dir ? whb : whf;
  int tid = threadIdx.x;
  int wv = tid >> 6, lane = tid & 63;
  int grp = wv >> 1;     // 0: rows 0..63, 1: rows 64..99
  int khalf = wv & 1;    // 0: k 0..51 (owner), 1: k 52..99
  int row = grp ? (64 + (lane < 36 ? lane : 35)) : lane;
  bool owns = grp ? (lane < 36) : true;
  long step = dir ? -(long)(T_ * 200) : (long)(T_ * 200);
  float* p = pre + ((long)(dir ? (B_ - 1) : 0) * T_ + t) * 200 + dir * 100;
  if (tid < 104) hb[0][tid] = 0.f;
  __syncthreads();
  if (khalf == 0) rnn_loop<0, 52, true >(p, step, row, owns, w, hb, ps);
  else            rnn_loop<52, 48, false>(p, step, row, owns, w, hb, ps);
}

// ---------------- K3: logits = h @ w_lin^T + b_lin ; softmax over 19. 2 rows/thread.
__global__ __launch_bounds__(256, 4) void k_lin(
    const float* __restrict__ h, const float* __restrict__ wlin,
    const float* __restrict__ blin, float* __restrict__ em) {
  int tid = threadIdx.x;
  long r0 = ((long)blockIdx.x * 256 + tid) * 2;
  const float* h0 = h + r0 * 200;
  float acc0[K_], acc1[K_];
#pragma unroll
  for (int c = 0; c < K_; c++) { float bb = blin[c]; acc0[c] = bb; acc1[c] = bb; }
  for (int kk = 0; kk < 50; kk++) {
    float4 a = *(const float4*)(h0 + 4 * kk);
    float4 b = *(const float4*)(h0 + 200 + 4 * kk);
#pragma unroll
    for (int c = 0; c < K_; c++) {
      float4 wv = *(const float4*)(wlin + c * 200 + 4 * kk);  // uniform -> s_load
      acc0[c] += a.x * wv.x + a.y * wv.y + a.z * wv.z + a.w * wv.w;
      acc1[c] += b.x * wv.x + b.y * wv.y + b.z * wv.z + b.w * wv.w;
    }
  }
  float mx0 = acc0[0], mx1 = acc1[0];
#pragma unroll
  for (int c = 1; c < K_; c++) { mx0 = fmaxf(mx0, acc0[c]); mx1 = fmaxf(mx1, acc1[c]); }
  float s0 = 0.f, s1 = 0.f;
#pragma unroll
  for (int c = 0; c < K_; c++) {
    acc0[c] = __expf(acc0[c] - mx0); s0 += acc0[c];
    acc1[c] = __expf(acc1[c] - mx1); s1 += acc1[c];
  }
  float i0 = 1.f / s0, i1 = 1.f / s1;
  float* e0 = em + r0 * K_;
#pragma unroll
  for (int c = 0; c < K_; c++) { e0[c] = acc0[c] * i0; e0[K_ + c] = acc1[c] * i1; }
}

// ---------------- K4: per-b CRF logZ + gold score (wave0) | Viterbi fwd + backtrack (wave1)
__global__ __launch_bounds__(128, 1) void k_crf(
    const float* __restrict__ em, const int* __restrict__ y,
    const float* __restrict__ st_g, const float* __restrict__ en_g,
    const float* __restrict__ tr_g,
    float* __restrict__ part, int* __restrict__ cnt,
    float* __restrict__ out) {
  __shared__ __align__(16) float es[T_ * K_];
  __shared__ int ys[T_];
  __shared__ float tr[K_ * K_];
  __shared__ float st[K_], en[K_];
  __shared__ unsigned char hl[511 * K_ + 13];
  __shared__ float lab[T_];
  int b = blockIdx.x;
  int tid = threadIdx.x;
  const float4* eb4 = (const float4*)(em + (long)b * T_ * K_);
  for (int u = tid; u < T_ * K_ / 4; u += 128) ((float4*)es)[u] = eb4[u];
  for (int u = tid; u < T_; u += 128) ys[u] = y[b * T_ + u];
  for (int u = tid; u < K_ * K_; u += 128) tr[u] = tr_g[u];
  if (tid < K_) { st[tid] = st_g[tid]; en[tid] = en_g[tid]; }
  __syncthreads();
  int wv = tid >> 6, lane = tid & 63;
  int jj = lane < K_ ? lane : K_ - 1;
  bool act = lane < K_;
  if (wv == 0) {
    float E[K_];
#pragma unroll
    for (int i = 0; i < K_; i++) E[i] = __expf(tr[i * K_ + jj]);
    float z = act ? st[jj] + es[jj] : -1e30f;
    int y0 = ys[0];
    int prev = (y0 != -1) ? y0 : 0;
    float num = st[prev] + es[prev];
    for (int t = 1; t < T_; t++) {
      float e = es[t * K_ + jj];
      int yv = ys[t];
      bool mb = (yv != -1);
      float m = z;
#pragma unroll
      for (int off = 16; off; off >>= 1) m = fmaxf(m, __shfl_xor(m, off, 32));
      float pz = __expf(z - m);
      float acca = 0.f, accb = 0.f;
#pragma unroll
      for (int i = 0; i < 9; i++)  acca = fmaf(rl_f(pz, i), E[i], acca);
#pragma unroll
      for (int i = 9; i < K_; i++) accb = fmaf(rl_f(pz, i), E[i], accb);
      float nz = e + m + __logf(acca + accb);
      if (act && mb) z = nz;
      if (mb) {
        num += tr[prev * K_ + yv] + es[t * K_ + yv];
        prev = yv;
      }
    }
    num += en[prev];
    float zf = z + en[jj];
    float m2 = zf;
#pragma unroll
    for (int off = 16; off; off >>= 1) m2 = fmaxf(m2, __shfl_xor(m2, off, 32));
    float sm = __expf(zf - m2);
#pragma unroll
    for (int off = 16; off; off >>= 1) sm += __shfl_xor(sm, off, 32);
    if (lane == 0) part[b] = m2 + __logf(sm) - num;
  } else {
    float Tt[K_];
#pragma unroll
    for (int i = 0; i < K_; i++) Tt[i] = tr[i * K_ + jj];
    float v = act ? st[jj] + es[jj] : -1e30f;
    for (int t = 1; t < T_; t++) {
      float e = es[t * K_ + jj];
      int yv = ys[t];
      bool mb = (yv != -1);
      float b0 = -1e30f, b1 = -1e30f, b2 = -1e30f, b3 = -1e30f;
      int a0 = 0, a1 = 5, a2 = 10, a3 = 15;
#pragma unroll
      for (int i = 0; i < 5; i++)  { float c = rl_f(v, i) + Tt[i]; if (c > b0) { b0 = c; a0 = i; } }
#pragma unroll
      for (int i = 5; i < 10; i++) { float c = rl_f(v, i) + Tt[i]; if (c > b1) { b1 = c; a1 = i; } }
#pragma unroll
      for (int i = 10; i < 15; i++){ float c = rl_f(v, i) + Tt[i]; if (c > b2) { b2 = c; a2 = i; } }
#pragma unroll
      for (int i = 15; i < 19; i++){ float c = rl_f(v, i) + Tt[i]; if (c > b3) { b3 = c; a3 = i; } }
      if (b1 > b0) { b0 = b1; a0 = a1; }
      if (b2 > b0) { b0 = b2; a0 = a2; }
      if (b3 > b0) { b0 = b3; a0 = a3; }
      if (act) hl[(t - 1) * K_ + lane] = (unsigned char)a0;
      if (act && mb) v = b0 + e;
    }
    float sc = v + en[jj];
    float bb = -1e30f; int aa = 0;
#pragma unroll
    for (int i = 0; i < K_; i++) { float c = rl_f(sc, i); if (c > bb) { bb = c; aa = i; } }
    int tag = aa;
    if (lane == 0) lab[T_ - 1] = (ys[T_ - 1] != -1) ? (float)tag : -1.f;
    int vc = (lane < K_) ? (int)hl[510 * K_ + lane] : 0;
    for (int ti = 510; ti >= 0; ti--) {
      int vn = 0;
      if (ti > 0 && lane < K_) vn = (int)hl[(ti - 1) * K_ + lane];
      int ts = __builtin_amdgcn_readfirstlane(tag);
      int cand = __builtin_amdgcn_readlane(vc, ts);
      tag = (ys[ti + 1] != -1) ? cand : tag;
      if (lane == 0) lab[ti] = (ys[ti] != -1) ? (float)tag : -1.f;
      vc = vn;
    }
  }
  __syncthreads();
  if (wv == 1) {
    float* ob = out + 1 + (long)b * T_;
    for (int u = lane; u < T_; u += 64) ob[u] = lab[u];
  } else {
    int old = -1;
    if (lane == 0) { __threadfence(); old = atomicAdd(cnt, 1); }
    old = __shfl(old, 0, 64);
    if (old == B_ - 1) {  // last block: deterministic fixed-order sum
      __threadfence();
      float s = 0.f;
      for (int u = lane; u < B_; u += 64) s += part[u];
#pragma unroll
      for (int off = 32; off; off >>= 1) s += __shfl_xor(s, off, 64);
      if (lane == 0) out[0] = s;
    }
  }
}

extern "C" void kernel_launch(void* const* d_in, const int* in_sizes, int n_in,
                              void* d_out, int out_size, void* d_ws, size_t ws_size,
                              hipStream_t stream) {
  const float* x      = (const float*)d_in[0];
  const int*   y      = (const int*)d_in[1];
  const float* w_ih_f = (const float*)d_in[2];
  const float* w_hh_f = (const float*)d_in[3];
  const float* b_ih_f = (const float*)d_in[4];
  const float* b_hh_f = (const float*)d_in[5];
  const float* w_ih_b = (const float*)d_in[6];
  const float* w_hh_b = (const float*)d_in[7];
  const float* b_ih_b = (const float*)d_in[8];
  const float* b_hh_b = (const float*)d_in[9];
  const float* w_lin  = (const float*)d_in[10];
  const float* b_lin  = (const float*)d_in[11];
  const float* st     = (const float*)d_in[12];
  const float* en     = (const float*)d_in[13];
  const float* trans  = (const float*)d_in[14];

  char* ws = (char*)d_ws;
  const size_t PRE_OFF  = 0;                          // 131072*200*4 = 104857600
  const size_t EM_OFF   = 104857600;                  // 131072*19*4  = 9961472
  const size_t PART_OFF = EM_OFF + 9961472;           // 1024
  const size_t CNT_OFF  = PART_OFF + 1024;            // 4
  float* PRE  = (float*)(ws + PRE_OFF);
  float* EM   = (float*)(ws + EM_OFF);
  float* PART = (float*)(ws + PART_OFF);
  int*   CNT  = (int*)(ws + CNT_OFF);
  float* out  = (float*)d_out;

  hipMemsetAsync((void*)CNT, 0, sizeof(int), stream);
  k_ih<<<1024, 256, 0, stream>>>(x, w_ih_f, w_ih_b, b_ih_f, b_hh_f, b_ih_b, b_hh_b, PRE);
  k_rnn<<<1024, 256, 0, stream>>>(PRE, w_hh_f, w_hh_b);
  k_lin<<<256, 256, 0, stream>>>(PRE, w_lin, b_lin, EM);
  k_crf<<<256, 128, 0, stream>>>(EM, y, st, en, trans, PART, CNT, out);
}

// Round 10
// 666.129 us; speedup vs baseline: 4.1945x; 1.1217x over previous
//
#include <hip/hip_runtime.h>
#include <hip/hip_bf16.h>

#define B_ 256
#define T_ 512
#define IN_ 202
#define HID_ 100
#define K_ 19

typedef __attribute__((ext_vector_type(8))) short short8v;
typedef __attribute__((ext_vector_type(4))) float f32x4;

__device__ __forceinline__ float rl_f(float v, int l) {
  return __int_as_float(__builtin_amdgcn_readlane(__float_as_int(v), l));
}

// ---------------- K0: split [wf;wb] (200x202) into 3 exact bf16 planes, padded to 224x224.
// w3[p][col][k], plane stride 50176. Truncation split: x0+x1+x2 == x exactly (24 mantissa bits).
__global__ __launch_bounds__(256, 1) void k_wprep(
    const float* __restrict__ wf, const float* __restrict__ wb,
    unsigned short* __restrict__ w3) {
  int idx = blockIdx.x * 256 + threadIdx.x;
  if (idx >= 224 * 224) return;
  int c = idx / 224, k = idx - (idx / 224) * 224;
  float v = 0.f;
  if (k < IN_) {
    if (c < 100) v = wf[c * IN_ + k];
    else if (c < 200) v = wb[(c - 100) * IN_ + k];
  }
  unsigned u0 = __float_as_uint(v) & 0xffff0000u;
  float r1 = v - __uint_as_float(u0);
  unsigned u1 = __float_as_uint(r1) & 0xffff0000u;
  float r2 = r1 - __uint_as_float(u1);
  w3[idx] = (unsigned short)(u0 >> 16);
  w3[50176 + idx] = (unsigned short)(u1 >> 16);
  w3[100352 + idx] = (unsigned short)(__float_as_uint(r2) >> 16);
}

// ---------------- K1: pre = x . [wf;wb]^T + bias via bf16-split MFMA.
// 512 blocks x 256 thr (4 waves). Block: 256 rows. Wave: 64 rows = 4 m-tiles.
// N = 224 (14 tiles) in 2 groups of 7 (K-loop inner per group; x restaged).
// A: row=lane&15, k=(lane>>4)*8+j (from LDS x-tile, pad 36). B from global w3
// (L2-resident). D: col=lane&15, row=(lane>>4)*4+reg. 8 split-products.
__global__ __launch_bounds__(256, 2) void k_ih(
    const float* __restrict__ x, const unsigned short* __restrict__ w3,
    const float* __restrict__ bif, const float* __restrict__ bhf,
    const float* __restrict__ bib, const float* __restrict__ bhb,
    float* __restrict__ pre) {
  __shared__ float xs[256 * 36];
  __shared__ float bsum[224];
  int tid = threadIdx.x;
  int wv = tid >> 6, l = tid & 63;
  long row0 = (long)blockIdx.x * 256;
  for (int u = tid; u < 224; u += 256) {
    float bv = 0.f;
    if (u < 100) bv = bif[u] + bhf[u];
    else if (u < 200) bv = bib[u - 100] + bhb[u - 100];
    bsum[u] = bv;
  }
  int lr = l & 15;   // A-row / B-col / D-col lane index
  int kq = l >> 4;   // k-group
  for (int g = 0; g < 2; g++) {
    f32x4 acc[4][7];
#pragma unroll
    for (int m = 0; m < 4; m++)
#pragma unroll
      for (int n = 0; n < 7; n++) acc[m][n] = (f32x4){0.f, 0.f, 0.f, 0.f};
    for (int ck = 0; ck < 7; ck++) {
      int k0 = ck * 32;
      __syncthreads();
#pragma unroll
      for (int i = 0; i < 16; i++) {
        int u = tid + i * 256;
        int r = u >> 4, kp = u & 15;
        int gk = k0 + 2 * kp;
        float2 v = make_float2(0.f, 0.f);
        if (gk < IN_) v = *(const float2*)(x + (row0 + r) * IN_ + gk);
        *(float2*)(&xs[r * 36 + 2 * kp]) = v;
      }
      __syncthreads();
      // build A fragments (exact 3-way bf16 split, in-register)
      short8v A0[4], A1[4], A2[4];
#pragma unroll
      for (int m = 0; m < 4; m++) {
        const float* ap = &xs[(wv * 64 + m * 16 + lr) * 36 + kq * 8];
        float4 fa = *(const float4*)(ap);
        float4 fb = *(const float4*)(ap + 4);
        float f[8] = {fa.x, fa.y, fa.z, fa.w, fb.x, fb.y, fb.z, fb.w};
#pragma unroll
        for (int j = 0; j < 8; j++) {
          unsigned u0 = __float_as_uint(f[j]) & 0xffff0000u;
          float r1 = f[j] - __uint_as_float(u0);
          unsigned u1 = __float_as_uint(r1) & 0xffff0000u;
          float r2 = r1 - __uint_as_float(u1);
          A0[m][j] = (short)(u0 >> 16);
          A1[m][j] = (short)(u1 >> 16);
          A2[m][j] = (short)(__float_as_uint(r2) >> 16);
        }
      }
#pragma unroll
      for (int n = 0; n < 7; n++) {
        int col = (g * 7 + n) * 16 + lr;
        const unsigned short* bp = w3 + (long)col * 224 + k0 + kq * 8;
        short8v B0 = *(const short8v*)(bp);
        short8v B1 = *(const short8v*)(bp + 50176);
        short8v B2 = *(const short8v*)(bp + 100352);
#pragma unroll
        for (int m = 0; m < 4; m++) {
          f32x4 c = acc[m][n];
          c = __builtin_amdgcn_mfma_f32_16x16x32_bf16(A0[m], B0, c, 0, 0, 0);
          c = __builtin_amdgcn_mfma_f32_16x16x32_bf16(A0[m], B1, c, 0, 0, 0);
          c = __builtin_amdgcn_mfma_f32_16x16x32_bf16(A1[m], B0, c, 0, 0, 0);
          c = __builtin_amdgcn_mfma_f32_16x16x32_bf16(A0[m], B2, c, 0, 0, 0);
          c = __builtin_amdgcn_mfma_f32_16x16x32_bf16(A2[m], B0, c, 0, 0, 0);
          c = __builtin_amdgcn_mfma_f32_16x16x32_bf16(A1[m], B1, c, 0, 0, 0);
          c = __builtin_amdgcn_mfma_f32_16x16x32_bf16(A1[m], B2, c, 0, 0, 0);
          c = __builtin_amdgcn_mfma_f32_16x16x32_bf16(A2[m], B1, c, 0, 0, 0);
          acc[m][n] = c;
        }
      }
    }
    // store group g
#pragma unroll
    for (int m = 0; m < 4; m++) {
      long rbase = row0 + wv * 64 + m * 16 + kq * 4;
#pragma unroll
      for (int n = 0; n < 7; n++) {
        int col = (g * 7 + n) * 16 + lr;
        if (col < 200) {
          float bv = bsum[col];
#pragma unroll
          for (int r = 0; r < 4; r++)
            pre[(rbase + r) * 200 + col] = acc[m][n][r] + bv;
        }
      }
    }
  }
}

// ---------------- K2: recurrence over b (256 steps); 4 waves per (t,dir) chain.
// Round-5 proven version (237 us).
template <int KO, int KN, bool OW>
__device__ __forceinline__ void rnn_loop(
    float* __restrict__ p, long step, int row, bool owns,
    const float* __restrict__ w, float (*hb)[104], float* __restrict__ ps) {
  float wr[KN];
#pragma unroll
  for (int i = 0; i < KN / 4; i++) {
    float4 w4 = *(const float4*)(w + row * HID_ + KO + 4 * i);
    wr[4 * i + 0] = w4.x; wr[4 * i + 1] = w4.y;
    wr[4 * i + 2] = w4.z; wr[4 * i + 3] = w4.w;
  }
  float a = 0.f;
  if (OW) a = p[row];
  for (int s = 0; s < B_; s++) {
    int cur = s & 1;
    float a_next = 0.f;
    if (OW && s < B_ - 1) a_next = p[step + row];
    float ac0 = OW ? a : 0.f, ac1 = 0.f, ac2 = 0.f, ac3 = 0.f;
#pragma unroll
    for (int i = 0; i < KN / 4; i++) {
      float4 h4 = *(const float4*)(&hb[cur][KO + 4 * i]);  // uniform addr -> broadcast
      ac0 = fmaf(h4.x, wr[4 * i + 0], ac0);
      ac1 = fmaf(h4.y, wr[4 * i + 1], ac1);
      ac2 = fmaf(h4.z, wr[4 * i + 2], ac2);
      ac3 = fmaf(h4.w, wr[4 * i + 3], ac3);
    }
    float partial = (ac0 + ac1) + (ac2 + ac3);
    if (!OW && owns) ps[row] = partial;
    __syncthreads();
    if (OW) {
      float hnew = tanhf(partial + ps[row]);
      if (owns) {
        hb[cur ^ 1][row] = hnew;
        p[row] = hnew;
      }
    }
    p += step;
    a = a_next;
    __syncthreads();
  }
}

__global__ __launch_bounds__(256, 4) void k_rnn(
    float* __restrict__ pre,
    const float* __restrict__ whf, const float* __restrict__ whb) {
  __shared__ float hb[2][104];
  __shared__ float ps[104];
  int bid = blockIdx.x;
  int dir = bid >> 9;
  int t = bid & 511;
  const float* w = dir ? whb : whf;
  int tid = threadIdx.x;
  int wv = tid >> 6, lane = tid & 63;
  int grp = wv >> 1;
  int khalf = wv & 1;
  int row = grp ? (64 + (lane < 36 ? lane : 35)) : lane;
  bool owns = grp ? (lane < 36) : true;
  long step = dir ? -(long)(T_ * 200) : (long)(T_ * 200);
  float* p = pre + ((long)(dir ? (B_ - 1) : 0) * T_ + t) * 200 + dir * 100;
  if (tid < 104) hb[0][tid] = 0.f;
  __syncthreads();
  if (khalf == 0) rnn_loop<0, 52, true >(p, step, row, owns, w, hb, ps);
  else            rnn_loop<52, 48, false>(p, step, row, owns, w, hb, ps);
}

// ---------------- K3: logits = h @ w_lin^T + b_lin ; softmax over 19. 2 rows/thread.
__global__ __launch_bounds__(256, 4) void k_lin(
    const float* __restrict__ h, const float* __restrict__ wlin,
    const float* __restrict__ blin, float* __restrict__ em) {
  int tid = threadIdx.x;
  long r0 = ((long)blockIdx.x * 256 + tid) * 2;
  const float* h0 = h + r0 * 200;
  float acc0[K_], acc1[K_];
#pragma unroll
  for (int c = 0; c < K_; c++) { float bb = blin[c]; acc0[c] = bb; acc1[c] = bb; }
  for (int kk = 0; kk < 50; kk++) {
    float4 a = *(const float4*)(h0 + 4 * kk);
    float4 b = *(const float4*)(h0 + 200 + 4 * kk);
#pragma unroll
    for (int c = 0; c < K_; c++) {
      float4 wv = *(const float4*)(wlin + c * 200 + 4 * kk);  // uniform -> s_load
      acc0[c] += a.x * wv.x + a.y * wv.y + a.z * wv.z + a.w * wv.w;
      acc1[c] += b.x * wv.x + b.y * wv.y + b.z * wv.z + b.w * wv.w;
    }
  }
  float mx0 = acc0[0], mx1 = acc1[0];
#pragma unroll
  for (int c = 1; c < K_; c++) { mx0 = fmaxf(mx0, acc0[c]); mx1 = fmaxf(mx1, acc1[c]); }
  float s0 = 0.f, s1 = 0.f;
#pragma unroll
  for (int c = 0; c < K_; c++) {
    acc0[c] = __expf(acc0[c] - mx0); s0 += acc0[c];
    acc1[c] = __expf(acc1[c] - mx1); s1 += acc1[c];
  }
  float i0 = 1.f / s0, i1 = 1.f / s1;
  float* e0 = em + r0 * K_;
#pragma unroll
  for (int c = 0; c < K_; c++) { e0[c] = acc0[c] * i0; e0[K_ + c] = acc1[c] * i1; }
}

// ---------------- K4: per-b CRF logZ + gold score (wave0) | Viterbi fwd + backtrack (wave1)
__global__ __launch_bounds__(128, 1) void k_crf(
    const float* __restrict__ em, const int* __restrict__ y,
    const float* __restrict__ st_g, const float* __restrict__ en_g,
    const float* __restrict__ tr_g,
    float* __restrict__ part, int* __restrict__ cnt,
    float* __restrict__ out) {
  __shared__ __align__(16) float es[T_ * K_];
  __shared__ int ys[T_];
  __shared__ float tr[K_ * K_];
  __shared__ float st[K_], en[K_];
  __shared__ unsigned char hl[511 * K_ + 13];
  __shared__ float lab[T_];
  int b = blockIdx.x;
  int tid = threadIdx.x;
  const float4* eb4 = (const float4*)(em + (long)b * T_ * K_);
  for (int u = tid; u < T_ * K_ / 4; u += 128) ((float4*)es)[u] = eb4[u];
  for (int u = tid; u < T_; u += 128) ys[u] = y[b * T_ + u];
  for (int u = tid; u < K_ * K_; u += 128) tr[u] = tr_g[u];
  if (tid < K_) { st[tid] = st_g[tid]; en[tid] = en_g[tid]; }
  __syncthreads();
  int wv = tid >> 6, lane = tid & 63;
  int jj = lane < K_ ? lane : K_ - 1;
  bool act = lane < K_;
  if (wv == 0) {
    float E[K_];
#pragma unroll
    for (int i = 0; i < K_; i++) E[i] = __expf(tr[i * K_ + jj]);
    float z = act ? st[jj] + es[jj] : -1e30f;
    int y0 = ys[0];
    int prev = (y0 != -1) ? y0 : 0;
    float num = st[prev] + es[prev];
    for (int t = 1; t < T_; t++) {
      float e = es[t * K_ + jj];
      int yv = ys[t];
      bool mb = (yv != -1);
      float m = z;
#pragma unroll
      for (int off = 16; off; off >>= 1) m = fmaxf(m, __shfl_xor(m, off, 32));
      float pz = __expf(z - m);
      float acca = 0.f, accb = 0.f;
#pragma unroll
      for (int i = 0; i < 9; i++)  acca = fmaf(rl_f(pz, i), E[i], acca);
#pragma unroll
      for (int i = 9; i < K_; i++) accb = fmaf(rl_f(pz, i), E[i], accb);
      float nz = e + m + __logf(acca + accb);
      if (act && mb) z = nz;
      if (mb) {
        num += tr[prev * K_ + yv] + es[t * K_ + yv];
        prev = yv;
      }
    }
    num += en[prev];
    float zf = z + en[jj];
    float m2 = zf;
#pragma unroll
    for (int off = 16; off; off >>= 1) m2 = fmaxf(m2, __shfl_xor(m2, off, 32));
    float sm = __expf(zf - m2);
#pragma unroll
    for (int off = 16; off; off >>= 1) sm += __shfl_xor(sm, off, 32);
    if (lane == 0) part[b] = m2 + __logf(sm) - num;
  } else {
    float Tt[K_];
#pragma unroll
    for (int i = 0; i < K_; i++) Tt[i] = tr[i * K_ + jj];
    float v = act ? st[jj] + es[jj] : -1e30f;
    for (int t = 1; t < T_; t++) {
      float e = es[t * K_ + jj];
      int yv = ys[t];
      bool mb = (yv != -1);
      float b0 = -1e30f, b1 = -1e30f, b2 = -1e30f, b3 = -1e30f;
      int a0 = 0, a1 = 5, a2 = 10, a3 = 15;
#pragma unroll
      for (int i = 0; i < 5; i++)  { float c = rl_f(v, i) + Tt[i]; if (c > b0) { b0 = c; a0 = i; } }
#pragma unroll
      for (int i = 5; i < 10; i++) { float c = rl_f(v, i) + Tt[i]; if (c > b1) { b1 = c; a1 = i; } }
#pragma unroll
      for (int i = 10; i < 15; i++){ float c = rl_f(v, i) + Tt[i]; if (c > b2) { b2 = c; a2 = i; } }
#pragma unroll
      for (int i = 15; i < 19; i++){ float c = rl_f(v, i) + Tt[i]; if (c > b3) { b3 = c; a3 = i; } }
      if (b1 > b0) { b0 = b1; a0 = a1; }
      if (b2 > b0) { b0 = b2; a0 = a2; }
      if (b3 > b0) { b0 = b3; a0 = a3; }
      if (act) hl[(t - 1) * K_ + lane] = (unsigned char)a0;
      if (act && mb) v = b0 + e;
    }
    float sc = v + en[jj];
    float bb = -1e30f; int aa = 0;
#pragma unroll
    for (int i = 0; i < K_; i++) { float c = rl_f(sc, i); if (c > bb) { bb = c; aa = i; } }
    int tag = aa;
    if (lane == 0) lab[T_ - 1] = (ys[T_ - 1] != -1) ? (float)tag : -1.f;
    int vc = (lane < K_) ? (int)hl[510 * K_ + lane] : 0;
    for (int ti = 510; ti >= 0; ti--) {
      int vn = 0;
      if (ti > 0 && lane < K_) vn = (int)hl[(ti - 1) * K_ + lane];
      int ts = __builtin_amdgcn_readfirstlane(tag);
      int cand = __builtin_amdgcn_readlane(vc, ts);
      tag = (ys[ti + 1] != -1) ? cand : tag;
      if (lane == 0) lab[ti] = (ys[ti] != -1) ? (float)tag : -1.f;
      vc = vn;
    }
  }
  __syncthreads();
  if (wv == 1) {
    float* ob = out + 1 + (long)b * T_;
    for (int u = lane; u < T_; u += 64) ob[u] = lab[u];
  } else {
    int old = -1;
    if (lane == 0) { __threadfence(); old = atomicAdd(cnt, 1); }
    old = __shfl(old, 0, 64);
    if (old == B_ - 1) {
      __threadfence();
      float s = 0.f;
      for (int u = lane; u < B_; u += 64) s += part[u];
#pragma unroll
      for (int off = 32; off; off >>= 1) s += __shfl_xor(s, off, 64);
      if (lane == 0) out[0] = s;
    }
  }
}

extern "C" void kernel_launch(void* const* d_in, const int* in_sizes, int n_in,
                              void* d_out, int out_size, void* d_ws, size_t ws_size,
                              hipStream_t stream) {
  const float* x      = (const float*)d_in[0];
  const int*   y      = (const int*)d_in[1];
  const float* w_ih_f = (const float*)d_in[2];
  const float* w_hh_f = (const float*)d_in[3];
  const float* b_ih_f = (const float*)d_in[4];
  const float* b_hh_f = (const float*)d_in[5];
  const float* w_ih_b = (const float*)d_in[6];
  const float* w_hh_b = (const float*)d_in[7];
  const float* b_ih_b = (const float*)d_in[8];
  const float* b_hh_b = (const float*)d_in[9];
  const float* w_lin  = (const float*)d_in[10];
  const float* b_lin  = (const float*)d_in[11];
  const float* st     = (const float*)d_in[12];
  const float* en     = (const float*)d_in[13];
  const float* trans  = (const float*)d_in[14];

  char* ws = (char*)d_ws;
  const size_t PRE_OFF  = 0;                          // 131072*200*4 = 104857600
  const size_t EM_OFF   = 104857600;                  // 131072*19*4  = 9961472
  const size_t PART_OFF = EM_OFF + 9961472;           // 1024
  const size_t CNT_OFF  = PART_OFF + 1024;            // 4
  float* PRE  = (float*)(ws + PRE_OFF);
  float* EM   = (float*)(ws + EM_OFF);
  float* PART = (float*)(ws + PART_OFF);
  int*   CNT  = (int*)(ws + CNT_OFF);
  // w3 bf16 planes live in the EM region (301056 B << 9.96 MB); k_ih consumes
  // them before k_lin overwrites EM. Zero extra workspace.
  unsigned short* W3 = (unsigned short*)(ws + EM_OFF);
  float* out  = (float*)d_out;

  hipMemsetAsync((void*)CNT, 0, sizeof(int), stream);
  k_wprep<<<196, 256, 0, stream>>>(w_ih_f, w_ih_b, W3);
  k_ih<<<512, 256, 0, stream>>>(x, W3, b_ih_f, b_hh_f, b_ih_b, b_hh_b, PRE);
  k_rnn<<<1024, 256, 0, stream>>>(PRE, w_hh_f, w_hh_b);
  k_lin<<<256, 256, 0, stream>>>(PRE, w_lin, b_lin, EM);
  k_crf<<<256, 128, 0, stream>>>(EM, y, st, en, trans, PART, CNT, out);
}